// Round 4
// baseline (504.603 us; speedup 1.0000x reference)
//
#include <hip/hip_runtime.h>
#include <hip/hip_bf16.h>

// DeformConvBlock B=4,C=64,H=W=256,OUT=64 — MFMA, barrier-free phase 2.
// K0: weights -> bf16 MFMA B-fragment order (ws).
// K1: x CHW fp32 -> NHWC bf16 (ws), LDS-free.
// K2: phase1 = offset conv via MFMA (A direct from xt); one __syncthreads;
//     phase2 = each thread gathers+blends ITS OWN A-fragment (channels
//     kc*32+lq*8 of pixel wv*64+pt*16+lm) -> no smp LDS, no per-tap
//     barriers, 16 lines/wave-load instead of 64.

typedef short short8 __attribute__((ext_vector_type(8)));
typedef float floatx4 __attribute__((ext_vector_type(4)));
typedef float f32x2 __attribute__((ext_vector_type(2)));

namespace {
constexpr int B_ = 4, C_ = 64, H_ = 256, W_ = 256, OUT_ = 64;
constexpr int HW_ = H_ * W_;
constexpr size_t XT_BYTES = (size_t)B_ * HW_ * C_ * 2;      // 32 MB NHWC bf16
constexpr size_t WOFF_OFF = XT_BYTES;                        // [9][2][2][64][8] bf16
constexpr int    WOFF_N   = 9 * 2 * 2 * 64 * 8;
constexpr size_t WDEF_OFF = WOFF_OFF + (size_t)WOFF_N * 2;   // [9][2][4][64][8] bf16
constexpr int    WDEF_N   = 9 * 2 * 4 * 64 * 8;
}

// ---------------- K0: weights -> B-fragment order (bf16) ----------------
__global__ void prep_weights(const float* __restrict__ w_off,
                             const float* __restrict__ w_def,
                             __hip_bfloat16* __restrict__ wof,
                             __hip_bfloat16* __restrict__ wdf)
{
    const int i0 = blockIdx.x * 256 + threadIdx.x;
    const int stride = gridDim.x * 256;
    for (int i = i0; i < WOFF_N; i += stride) {
        const int jj = i & 7, lane = (i >> 3) & 63, nt = (i >> 9) & 1;
        const int kc = (i >> 10) & 1, tap = i >> 11;
        const int c = kc * 32 + (lane >> 4) * 8 + jj;
        const int n = nt * 16 + (lane & 15);
        const float v = (n < 18) ? w_off[(n * 64 + c) * 9 + tap] : 0.0f;
        wof[i] = __float2bfloat16(v);
    }
    for (int i = i0; i < WDEF_N; i += stride) {
        const int jj = i & 7, lane = (i >> 3) & 63, ot = (i >> 9) & 3;
        const int kc = (i >> 11) & 1, tap = i >> 12;
        const int c = kc * 32 + (lane >> 4) * 8 + jj;
        const int n = ot * 16 + (lane & 15);
        wdf[i] = __float2bfloat16(w_def[(n * 64 + c) * 9 + tap]);
    }
}

// ---------------- K1: x CHW fp32 -> NHWC bf16, LDS-free ----------------
__global__ __launch_bounds__(256)
void transpose_x(const float* __restrict__ x, __hip_bfloat16* __restrict__ xt)
{
    const int y = blockIdx.x & 255, b = blockIdx.x >> 8;
    const int px = threadIdx.x;
    const float* __restrict__ xp = x + (size_t)b * C_ * HW_ + y * W_ + px;
    union { __hip_bfloat16 h[64]; uint4 u[8]; } buf;
#pragma unroll
    for (int c = 0; c < 64; ++c)
        buf.h[c] = __float2bfloat16(xp[(size_t)c * HW_]);   // lanes sweep px: coalesced
    uint4* __restrict__ dst = (uint4*)(xt + (((size_t)(b * H_ + y)) * W_ + px) * C_);
#pragma unroll
    for (int k = 0; k < 8; ++k) dst[k] = buf.u[k];          // 128 B contiguous per lane
}

// ---------------- K2 helpers ----------------
__device__ __forceinline__ void bilin_setup(float ys, float xs, int* a, float* w)
{
    const float y0f = floorf(ys), x0f = floorf(xs);
    const float ly = ys - y0f, lx = xs - x0f;
    const int y0 = (int)y0f, x0 = (int)x0f;
    const int y1 = y0 + 1, x1 = x0 + 1;
    const int y0c = min(max(y0, 0), H_ - 1);
    const int y1c = min(max(y1, 0), H_ - 1);
    const int x0c = min(max(x0, 0), W_ - 1);
    const int x1c = min(max(x1, 0), W_ - 1);
    const float fy0 = (y0 >= 0 && y0 < H_) ? 1.0f : 0.0f;
    const float fy1 = (y1 >= 0 && y1 < H_) ? 1.0f : 0.0f;
    const float fx0 = (x0 >= 0 && x0 < W_) ? 1.0f : 0.0f;
    const float fx1 = (x1 >= 0 && x1 < W_) ? 1.0f : 0.0f;
    a[0] = y0c * W_ + x0c;  w[0] = (1.0f - ly) * (1.0f - lx) * fy0 * fx0;
    a[1] = y0c * W_ + x1c;  w[1] = (1.0f - ly) * lx          * fy0 * fx1;
    a[2] = y1c * W_ + x0c;  w[2] = ly          * (1.0f - lx) * fy1 * fx0;
    a[3] = y1c * W_ + x1c;  w[3] = ly          * lx          * fy1 * fx1;
}

// ---------------- K2: fused deform conv (MFMA, barrier-free) ----------------
__global__ __launch_bounds__(256, 4)
void deform_main(const __hip_bfloat16* __restrict__ xt,
                 const __hip_bfloat16* __restrict__ wof,
                 const float* __restrict__ b_off,
                 const __hip_bfloat16* __restrict__ wdf,
                 const float* __restrict__ b_def,
                 float* __restrict__ out)
{
    __shared__ float off_lds[256 * 18];       // per-pixel offsets (wave-private use)

    const int tid = threadIdx.x;
    const int lane = tid & 63;
    const int wv = tid >> 6;            // wave id: px range [wv*64, wv*64+64)
    const int lm = lane & 15;
    const int lq = lane >> 4;
    const int bid = blockIdx.x;
    const int row = (bid & 7) * 128 + (bid >> 3);   // XCD band swizzle
    const int b = row >> 8, y = row & 255;
    const __hip_bfloat16* __restrict__ xtb = xt + (size_t)b * HW_ * C_;

    // ================= phase 1: offsets via MFMA =================
    {
        floatx4 acc1[4][2];
#pragma unroll
        for (int pt = 0; pt < 4; ++pt)
#pragma unroll
            for (int nt = 0; nt < 2; ++nt) acc1[pt][nt] = (floatx4)0.0f;

#pragma unroll 1
        for (int tap = 0; tap < 9; ++tap) {
            const int dy = tap / 3 - 1, dx = tap % 3 - 1;
            const int ys = y + dy;
            if ((unsigned)ys < 256u) {
#pragma unroll
                for (int kc = 0; kc < 2; ++kc) {
                    short8 bfr[2];
#pragma unroll
                    for (int nt = 0; nt < 2; ++nt)
                        bfr[nt] = *(const short8*)(wof +
                            ((size_t)(((tap * 2 + kc) * 2 + nt) * 64 + lane)) * 8);
                    short8 afr[4];
#pragma unroll
                    for (int pt = 0; pt < 4; ++pt) {
                        const int px_s = wv * 64 + pt * 16 + lm + dx;
                        const bool vld = (unsigned)px_s < 256u;
                        const int pxc = min(max(px_s, 0), 255);
                        uint4 t = *(const uint4*)(xtb +
                            ((size_t)ys * 256 + pxc) * 64 + kc * 32 + lq * 8);
                        if (!vld) { t.x = 0u; t.y = 0u; t.z = 0u; t.w = 0u; }
                        afr[pt] = __builtin_bit_cast(short8, t);
                    }
#pragma unroll
                    for (int pt = 0; pt < 4; ++pt)
#pragma unroll
                        for (int nt = 0; nt < 2; ++nt)
                            acc1[pt][nt] = __builtin_amdgcn_mfma_f32_16x16x32_bf16(
                                afr[pt], bfr[nt], acc1[pt][nt], 0, 0, 0);
                }
            }
        }
#pragma unroll
        for (int nt = 0; nt < 2; ++nt) {
            const int j = nt * 16 + lm;
            if (j < 18) {
                const float bj = b_off[j];
#pragma unroll
                for (int pt = 0; pt < 4; ++pt) {
#pragma unroll
                    for (int r = 0; r < 4; ++r) {
                        const int px = wv * 64 + pt * 16 + lq * 4 + r;
                        off_lds[px * 18 + j] = acc1[pt][nt][r] + bj;
                    }
                }
            }
        }
    }
    __syncthreads();   // the ONLY barrier

    // ================= phase 2: per-thread A-frag gather + MFMA =================
    floatx4 acc[4][4];
#pragma unroll
    for (int pt = 0; pt < 4; ++pt)
#pragma unroll
        for (int ot = 0; ot < 4; ++ot) acc[pt][ot] = (floatx4)0.0f;

#pragma unroll 1
    for (int tap = 0; tap < 9; ++tap) {
        const int ki = tap / 3, kj = tap % 3;
        float ys[4], xs[4];
#pragma unroll
        for (int pt = 0; pt < 4; ++pt) {
            const int apx = wv * 64 + pt * 16 + lm;
            ys[pt] = (float)(y + ki - 1) + off_lds[apx * 18 + tap * 2];
            xs[pt] = (float)(apx + kj - 1) + off_lds[apx * 18 + tap * 2 + 1];
        }

#pragma unroll
        for (int kc = 0; kc < 2; ++kc) {
            short8 bfr[4];
#pragma unroll
            for (int ot = 0; ot < 4; ++ot)
                bfr[ot] = *(const short8*)(wdf +
                    ((size_t)(((tap * 2 + kc) * 4 + ot) * 64 + lane)) * 8);

            short8 afr[4];
            const int sub = kc * 32 + lq * 8;
#pragma unroll
            for (int pt = 0; pt < 4; ++pt) {
                int ca[4]; float cw[4];
                bilin_setup(ys[pt], xs[pt], ca, cw);
                const uint4 u0 = *(const uint4*)(xtb + (size_t)ca[0] * 64 + sub);
                const uint4 u1 = *(const uint4*)(xtb + (size_t)ca[1] * 64 + sub);
                const uint4 u2 = *(const uint4*)(xtb + (size_t)ca[2] * 64 + sub);
                const uint4 u3 = *(const uint4*)(xtb + (size_t)ca[3] * 64 + sub);
                const unsigned* A = &u0.x;
                const unsigned* Bp = &u1.x;
                const unsigned* Cc = &u2.x;
                const unsigned* D = &u3.x;
                union { short8 v; short h[8]; } r;
#pragma unroll
                for (int k = 0; k < 4; ++k) {
                    f32x2 va, vb, vc, vd;
                    va.x = __uint_as_float(A[k] << 16);
                    va.y = __uint_as_float(A[k] & 0xffff0000u);
                    vb.x = __uint_as_float(Bp[k] << 16);
                    vb.y = __uint_as_float(Bp[k] & 0xffff0000u);
                    vc.x = __uint_as_float(Cc[k] << 16);
                    vc.y = __uint_as_float(Cc[k] & 0xffff0000u);
                    vd.x = __uint_as_float(D[k] << 16);
                    vd.y = __uint_as_float(D[k] & 0xffff0000u);
                    const f32x2 s = (f32x2)(cw[0]) * va + (f32x2)(cw[1]) * vb
                                  + (f32x2)(cw[2]) * vc + (f32x2)(cw[3]) * vd;
                    r.h[2 * k]     = __builtin_bit_cast(short, __float2bfloat16(s.x));
                    r.h[2 * k + 1] = __builtin_bit_cast(short, __float2bfloat16(s.y));
                }
                afr[pt] = r.v;
            }
#pragma unroll
            for (int pt = 0; pt < 4; ++pt)
#pragma unroll
                for (int ot = 0; ot < 4; ++ot)
                    acc[pt][ot] = __builtin_amdgcn_mfma_f32_16x16x32_bf16(
                        afr[pt], bfr[ot], acc[pt][ot], 0, 0, 0);
        }
    }

    // ================= epilogue: float4 stores =================
#pragma unroll
    for (int ot = 0; ot < 4; ++ot) {
        const int o = ot * 16 + lm;
        const float bd = b_def[o];
#pragma unroll
        for (int pt = 0; pt < 4; ++pt) {
            const int pxs = wv * 64 + pt * 16 + lq * 4;
            const floatx4 a = acc[pt][ot];
            float4 v = make_float4(a[0] + bd, a[1] + bd, a[2] + bd, a[3] + bd);
            *(float4*)&out[(((size_t)b * OUT_ + o) * H_ + y) * W_ + pxs] = v;
        }
    }
}

extern "C" void kernel_launch(void* const* d_in, const int* in_sizes, int n_in,
                              void* d_out, int out_size, void* d_ws, size_t ws_size,
                              hipStream_t stream)
{
    const float* x     = (const float*)d_in[0];
    const float* w_off = (const float*)d_in[1];
    const float* b_off = (const float*)d_in[2];
    const float* w_def = (const float*)d_in[3];
    const float* b_def = (const float*)d_in[4];
    float* out = (float*)d_out;

    __hip_bfloat16* xt  = (__hip_bfloat16*)d_ws;
    __hip_bfloat16* wof = (__hip_bfloat16*)((char*)d_ws + WOFF_OFF);
    __hip_bfloat16* wdf = (__hip_bfloat16*)((char*)d_ws + WDEF_OFF);

    prep_weights<<<dim3(32), dim3(256), 0, stream>>>(w_off, w_def, wof, wdf);
    transpose_x<<<dim3(B_ * H_), dim3(256), 0, stream>>>(x, xt);
    deform_main<<<dim3(B_ * H_), dim3(256), 0, stream>>>(
        xt, wof, b_off, wdf, b_def, out);
}

// Round 5
// 311.184 us; speedup vs baseline: 1.6216x; 1.6216x over previous
//
#include <hip/hip_runtime.h>
#include <hip/hip_bf16.h>

// DeformConvBlock B=4,C=64,H=W=256,OUT=64 — MFMA, barrier-free phase 2.
// R5: fix R4's spill (launch_bounds(256,3): 64 AGPR acc + ~100 arch VGPR
// fits the 168-reg budget; R4's (256,4)=128 left 64 arch regs -> 812 MB
// scratch traffic). MFMAs issued per-pt to cut afr live range. transpose_x
// back to the LDS version (contiguous wave stores).

typedef short short8 __attribute__((ext_vector_type(8)));
typedef float floatx4 __attribute__((ext_vector_type(4)));
typedef float f32x2 __attribute__((ext_vector_type(2)));

namespace {
constexpr int B_ = 4, C_ = 64, H_ = 256, W_ = 256, OUT_ = 64;
constexpr int HW_ = H_ * W_;
constexpr size_t XT_BYTES = (size_t)B_ * HW_ * C_ * 2;      // 32 MB NHWC bf16
constexpr size_t WOFF_OFF = XT_BYTES;                        // [9][2][2][64][8] bf16
constexpr int    WOFF_N   = 9 * 2 * 2 * 64 * 8;
constexpr size_t WDEF_OFF = WOFF_OFF + (size_t)WOFF_N * 2;   // [9][2][4][64][8] bf16
constexpr int    WDEF_N   = 9 * 2 * 4 * 64 * 8;
}

// ---------------- K0: weights -> B-fragment order (bf16) ----------------
__global__ void prep_weights(const float* __restrict__ w_off,
                             const float* __restrict__ w_def,
                             __hip_bfloat16* __restrict__ wof,
                             __hip_bfloat16* __restrict__ wdf)
{
    const int i0 = blockIdx.x * 256 + threadIdx.x;
    const int stride = gridDim.x * 256;
    for (int i = i0; i < WOFF_N; i += stride) {
        const int jj = i & 7, lane = (i >> 3) & 63, nt = (i >> 9) & 1;
        const int kc = (i >> 10) & 1, tap = i >> 11;
        const int c = kc * 32 + (lane >> 4) * 8 + jj;
        const int n = nt * 16 + (lane & 15);
        const float v = (n < 18) ? w_off[(n * 64 + c) * 9 + tap] : 0.0f;
        wof[i] = __float2bfloat16(v);
    }
    for (int i = i0; i < WDEF_N; i += stride) {
        const int jj = i & 7, lane = (i >> 3) & 63, ot = (i >> 9) & 3;
        const int kc = (i >> 11) & 1, tap = i >> 12;
        const int c = kc * 32 + (lane >> 4) * 8 + jj;
        const int n = ot * 16 + (lane & 15);
        wdf[i] = __float2bfloat16(w_def[(n * 64 + c) * 9 + tap]);
    }
}

// ---------------- K1: x CHW fp32 -> NHWC bf16 (LDS, coalesced both ways) ----
__global__ __launch_bounds__(256)
void transpose_x(const float* __restrict__ x, __hip_bfloat16* __restrict__ xt)
{
    __shared__ float tile[64 * 65];
    const int bid = blockIdx.x;           // ((b*256+y)*4 + xchunk)
    const int xc = bid & 3;
    const int y = (bid >> 2) & 255;
    const int b = bid >> 10;
    const int px0 = xc * 64;
    const float* __restrict__ xp = x + (size_t)b * C_ * HW_ + y * W_ + px0;

    for (int i = threadIdx.x; i < 64 * 64; i += 256) {
        const int c = i >> 6, px = i & 63;
        tile[px * 65 + c] = xp[(size_t)c * HW_ + px];
    }
    __syncthreads();

    const int px = threadIdx.x >> 2;
    const int cs = (threadIdx.x & 3) * 16;
    __hip_bfloat16 hv[16];
#pragma unroll
    for (int k = 0; k < 16; ++k) hv[k] = __float2bfloat16(tile[px * 65 + cs + k]);
    __hip_bfloat16* dst = xt + (((size_t)(b * H_ + y)) * W_ + px0 + px) * C_ + cs;
    ((uint4*)dst)[0] = ((const uint4*)hv)[0];
    ((uint4*)dst)[1] = ((const uint4*)hv)[1];
}

// ---------------- K2 helpers ----------------
__device__ __forceinline__ void bilin_setup(float ys, float xs, int* a, float* w)
{
    const float y0f = floorf(ys), x0f = floorf(xs);
    const float ly = ys - y0f, lx = xs - x0f;
    const int y0 = (int)y0f, x0 = (int)x0f;
    const int y1 = y0 + 1, x1 = x0 + 1;
    const int y0c = min(max(y0, 0), H_ - 1);
    const int y1c = min(max(y1, 0), H_ - 1);
    const int x0c = min(max(x0, 0), W_ - 1);
    const int x1c = min(max(x1, 0), W_ - 1);
    const float fy0 = (y0 >= 0 && y0 < H_) ? 1.0f : 0.0f;
    const float fy1 = (y1 >= 0 && y1 < H_) ? 1.0f : 0.0f;
    const float fx0 = (x0 >= 0 && x0 < W_) ? 1.0f : 0.0f;
    const float fx1 = (x1 >= 0 && x1 < W_) ? 1.0f : 0.0f;
    a[0] = y0c * W_ + x0c;  w[0] = (1.0f - ly) * (1.0f - lx) * fy0 * fx0;
    a[1] = y0c * W_ + x1c;  w[1] = (1.0f - ly) * lx          * fy0 * fx1;
    a[2] = y1c * W_ + x0c;  w[2] = ly          * (1.0f - lx) * fy1 * fx0;
    a[3] = y1c * W_ + x1c;  w[3] = ly          * lx          * fy1 * fx1;
}

// ---------------- K2: fused deform conv (MFMA, barrier-free) ----------------
__global__ __launch_bounds__(256, 3)
void deform_main(const __hip_bfloat16* __restrict__ xt,
                 const __hip_bfloat16* __restrict__ wof,
                 const float* __restrict__ b_off,
                 const __hip_bfloat16* __restrict__ wdf,
                 const float* __restrict__ b_def,
                 float* __restrict__ out)
{
    __shared__ float off_lds[256 * 18];       // per-pixel offsets

    const int tid = threadIdx.x;
    const int lane = tid & 63;
    const int wv = tid >> 6;            // wave id: px range [wv*64, wv*64+64)
    const int lm = lane & 15;
    const int lq = lane >> 4;
    const int bid = blockIdx.x;
    const int row = (bid & 7) * 128 + (bid >> 3);   // XCD band swizzle
    const int b = row >> 8, y = row & 255;
    const __hip_bfloat16* __restrict__ xtb = xt + (size_t)b * HW_ * C_;

    // ================= phase 1: offsets via MFMA =================
    {
        floatx4 acc1[4][2];
#pragma unroll
        for (int pt = 0; pt < 4; ++pt)
#pragma unroll
            for (int nt = 0; nt < 2; ++nt) acc1[pt][nt] = (floatx4)0.0f;

#pragma unroll 1
        for (int tap = 0; tap < 9; ++tap) {
            const int dy = tap / 3 - 1, dx = tap % 3 - 1;
            const int ys = y + dy;
            if ((unsigned)ys < 256u) {
#pragma unroll
                for (int kc = 0; kc < 2; ++kc) {
                    short8 bfr[2];
#pragma unroll
                    for (int nt = 0; nt < 2; ++nt)
                        bfr[nt] = *(const short8*)(wof +
                            ((size_t)(((tap * 2 + kc) * 2 + nt) * 64 + lane)) * 8);
#pragma unroll
                    for (int pt = 0; pt < 4; ++pt) {
                        const int px_s = wv * 64 + pt * 16 + lm + dx;
                        const bool vld = (unsigned)px_s < 256u;
                        const int pxc = min(max(px_s, 0), 255);
                        uint4 t = *(const uint4*)(xtb +
                            ((size_t)ys * 256 + pxc) * 64 + kc * 32 + lq * 8);
                        if (!vld) { t.x = 0u; t.y = 0u; t.z = 0u; t.w = 0u; }
                        const short8 afr = __builtin_bit_cast(short8, t);
#pragma unroll
                        for (int nt = 0; nt < 2; ++nt)
                            acc1[pt][nt] = __builtin_amdgcn_mfma_f32_16x16x32_bf16(
                                afr, bfr[nt], acc1[pt][nt], 0, 0, 0);
                    }
                }
            }
        }
#pragma unroll
        for (int nt = 0; nt < 2; ++nt) {
            const int j = nt * 16 + lm;
            if (j < 18) {
                const float bj = b_off[j];
#pragma unroll
                for (int pt = 0; pt < 4; ++pt) {
#pragma unroll
                    for (int r = 0; r < 4; ++r) {
                        const int px = wv * 64 + pt * 16 + lq * 4 + r;
                        off_lds[px * 18 + j] = acc1[pt][nt][r] + bj;
                    }
                }
            }
        }
    }
    __syncthreads();   // the ONLY barrier

    // ================= phase 2: per-thread A-frag gather + MFMA =================
    floatx4 acc[4][4];
#pragma unroll
    for (int pt = 0; pt < 4; ++pt)
#pragma unroll
        for (int ot = 0; ot < 4; ++ot) acc[pt][ot] = (floatx4)0.0f;

#pragma unroll 1
    for (int tap = 0; tap < 9; ++tap) {
        const int ki = tap / 3, kj = tap % 3;
        float ys[4], xs[4];
#pragma unroll
        for (int pt = 0; pt < 4; ++pt) {
            const int apx = wv * 64 + pt * 16 + lm;
            ys[pt] = (float)(y + ki - 1) + off_lds[apx * 18 + tap * 2];
            xs[pt] = (float)(apx + kj - 1) + off_lds[apx * 18 + tap * 2 + 1];
        }

#pragma unroll
        for (int kc = 0; kc < 2; ++kc) {
            short8 bfr[4];
#pragma unroll
            for (int ot = 0; ot < 4; ++ot)
                bfr[ot] = *(const short8*)(wdf +
                    ((size_t)(((tap * 2 + kc) * 4 + ot) * 64 + lane)) * 8);

            const int sub = kc * 32 + lq * 8;
#pragma unroll
            for (int pt = 0; pt < 4; ++pt) {
                int ca[4]; float cw[4];
                bilin_setup(ys[pt], xs[pt], ca, cw);
                const uint4 u0 = *(const uint4*)(xtb + (size_t)ca[0] * 64 + sub);
                const uint4 u1 = *(const uint4*)(xtb + (size_t)ca[1] * 64 + sub);
                const uint4 u2 = *(const uint4*)(xtb + (size_t)ca[2] * 64 + sub);
                const uint4 u3 = *(const uint4*)(xtb + (size_t)ca[3] * 64 + sub);
                const unsigned* A = &u0.x;
                const unsigned* Bp = &u1.x;
                const unsigned* Cc = &u2.x;
                const unsigned* D = &u3.x;
                union { short8 v; short h[8]; } r;
#pragma unroll
                for (int k = 0; k < 4; ++k) {
                    f32x2 va, vb, vc, vd;
                    va.x = __uint_as_float(A[k] << 16);
                    va.y = __uint_as_float(A[k] & 0xffff0000u);
                    vb.x = __uint_as_float(Bp[k] << 16);
                    vb.y = __uint_as_float(Bp[k] & 0xffff0000u);
                    vc.x = __uint_as_float(Cc[k] << 16);
                    vc.y = __uint_as_float(Cc[k] & 0xffff0000u);
                    vd.x = __uint_as_float(D[k] << 16);
                    vd.y = __uint_as_float(D[k] & 0xffff0000u);
                    const f32x2 s = (f32x2)(cw[0]) * va + (f32x2)(cw[1]) * vb
                                  + (f32x2)(cw[2]) * vc + (f32x2)(cw[3]) * vd;
                    r.h[2 * k]     = __builtin_bit_cast(short, __float2bfloat16(s.x));
                    r.h[2 * k + 1] = __builtin_bit_cast(short, __float2bfloat16(s.y));
                }
                const short8 afr = r.v;
#pragma unroll
                for (int ot = 0; ot < 4; ++ot)
                    acc[pt][ot] = __builtin_amdgcn_mfma_f32_16x16x32_bf16(
                        afr, bfr[ot], acc[pt][ot], 0, 0, 0);
            }
        }
    }

    // ================= epilogue: float4 stores =================
#pragma unroll
    for (int ot = 0; ot < 4; ++ot) {
        const int o = ot * 16 + lm;
        const float bd = b_def[o];
#pragma unroll
        for (int pt = 0; pt < 4; ++pt) {
            const int pxs = wv * 64 + pt * 16 + lq * 4;
            const floatx4 a = acc[pt][ot];
            float4 v = make_float4(a[0] + bd, a[1] + bd, a[2] + bd, a[3] + bd);
            *(float4*)&out[(((size_t)b * OUT_ + o) * H_ + y) * W_ + pxs] = v;
        }
    }
}

extern "C" void kernel_launch(void* const* d_in, const int* in_sizes, int n_in,
                              void* d_out, int out_size, void* d_ws, size_t ws_size,
                              hipStream_t stream)
{
    const float* x     = (const float*)d_in[0];
    const float* w_off = (const float*)d_in[1];
    const float* b_off = (const float*)d_in[2];
    const float* w_def = (const float*)d_in[3];
    const float* b_def = (const float*)d_in[4];
    float* out = (float*)d_out;

    __hip_bfloat16* xt  = (__hip_bfloat16*)d_ws;
    __hip_bfloat16* wof = (__hip_bfloat16*)((char*)d_ws + WOFF_OFF);
    __hip_bfloat16* wdf = (__hip_bfloat16*)((char*)d_ws + WDEF_OFF);

    prep_weights<<<dim3(32), dim3(256), 0, stream>>>(w_off, w_def, wof, wdf);
    transpose_x<<<dim3(B_ * H_ * 4), dim3(256), 0, stream>>>(x, xt);
    deform_main<<<dim3(B_ * H_), dim3(256), 0, stream>>>(
        xt, wof, b_off, wdf, b_def, out);
}

// Round 6
// 299.299 us; speedup vs baseline: 1.6860x; 1.0397x over previous
//
#include <hip/hip_runtime.h>

// DeformConvBlock B=4,C=64,H=W=256,OUT=64 — fp16 MFMA pipeline.
// R6: bf16 -> fp16 everywhere. Blend done in packed-f16 (v_pk_fma_f16):
// corners stay packed, result IS the A-frag (no unpack/repack). Wave tile
// 32px x 64out (acc=32 AGPR) + block=128px so launch_bounds(256,4) fits
// (16 waves/CU, grid 2048 = exactly 2 rounds). Weight prep fused into
// transpose kernel.

typedef _Float16 half8 __attribute__((ext_vector_type(8)));
typedef _Float16 h2    __attribute__((ext_vector_type(2)));
typedef float floatx4  __attribute__((ext_vector_type(4)));

namespace {
constexpr int B_ = 4, C_ = 64, H_ = 256, W_ = 256, OUT_ = 64;
constexpr int HW_ = H_ * W_;
constexpr size_t XT_BYTES = (size_t)B_ * HW_ * C_ * 2;      // 32 MB NHWC f16
constexpr size_t WOFF_OFF = XT_BYTES;                        // [9][2][2][64][8] f16
constexpr int    WOFF_N   = 9 * 2 * 2 * 64 * 8;
constexpr size_t WDEF_OFF = WOFF_OFF + (size_t)WOFF_N * 2;   // [9][2][4][64][8] f16
constexpr int    WDEF_N   = 9 * 2 * 4 * 64 * 8;
}

// ------- K1: x CHW f32 -> NHWC f16 (+ weight prep in first 32 blocks) -------
__global__ __launch_bounds__(256)
void transpose_x(const float* __restrict__ x, _Float16* __restrict__ xt,
                 const float* __restrict__ w_off, const float* __restrict__ w_def,
                 _Float16* __restrict__ wof, _Float16* __restrict__ wdf)
{
    __shared__ float tile[64 * 65];
    const int bid = blockIdx.x;           // ((b*256+y)*4 + xchunk)
    const int xc = bid & 3;
    const int y = (bid >> 2) & 255;
    const int b = bid >> 10;
    const int px0 = xc * 64;
    const float* __restrict__ xp = x + (size_t)b * C_ * HW_ + y * W_ + px0;

    for (int i = threadIdx.x; i < 64 * 64; i += 256) {
        const int c = i >> 6, px = i & 63;
        tile[px * 65 + c] = xp[(size_t)c * HW_ + px];
    }
    __syncthreads();

    const int px = threadIdx.x >> 2;
    const int cs = (threadIdx.x & 3) * 16;
    union { _Float16 h[16]; uint4 u[2]; } buf;
#pragma unroll
    for (int k = 0; k < 16; ++k) buf.h[k] = (_Float16)tile[px * 65 + cs + k];
    _Float16* dst = xt + (((size_t)(b * H_ + y)) * W_ + px0 + px) * C_ + cs;
    ((uint4*)dst)[0] = buf.u[0];
    ((uint4*)dst)[1] = buf.u[1];

    // ---- weight prep (blocks 0..31) ----
    if (bid < 32) {
        const int i0 = bid * 256 + threadIdx.x;
        for (int i = i0; i < WOFF_N; i += 32 * 256) {
            const int jj = i & 7, lane = (i >> 3) & 63, nt = (i >> 9) & 1;
            const int kc = (i >> 10) & 1, tap = i >> 11;
            const int c = kc * 32 + (lane >> 4) * 8 + jj;
            const int n = nt * 16 + (lane & 15);
            const float v = (n < 18) ? w_off[(n * 64 + c) * 9 + tap] : 0.0f;
            wof[i] = (_Float16)v;
        }
        for (int i = i0; i < WDEF_N; i += 32 * 256) {
            const int jj = i & 7, lane = (i >> 3) & 63, ot = (i >> 9) & 3;
            const int kc = (i >> 11) & 1, tap = i >> 12;
            const int c = kc * 32 + (lane >> 4) * 8 + jj;
            const int n = ot * 16 + (lane & 15);
            wdf[i] = (_Float16)w_def[(n * 64 + c) * 9 + tap];
        }
    }
}

// ---------------- K2 helpers ----------------
__device__ __forceinline__ void bilin_setup(float ys, float xs, int* a, float* w)
{
    const float y0f = floorf(ys), x0f = floorf(xs);
    const float ly = ys - y0f, lx = xs - x0f;
    const int y0 = (int)y0f, x0 = (int)x0f;
    const int y1 = y0 + 1, x1 = x0 + 1;
    const int y0c = min(max(y0, 0), H_ - 1);
    const int y1c = min(max(y1, 0), H_ - 1);
    const int x0c = min(max(x0, 0), W_ - 1);
    const int x1c = min(max(x1, 0), W_ - 1);
    const float fy0 = (y0 >= 0 && y0 < H_) ? 1.0f : 0.0f;
    const float fy1 = (y1 >= 0 && y1 < H_) ? 1.0f : 0.0f;
    const float fx0 = (x0 >= 0 && x0 < W_) ? 1.0f : 0.0f;
    const float fx1 = (x1 >= 0 && x1 < W_) ? 1.0f : 0.0f;
    a[0] = y0c * W_ + x0c;  w[0] = (1.0f - ly) * (1.0f - lx) * fy0 * fx0;
    a[1] = y0c * W_ + x1c;  w[1] = (1.0f - ly) * lx          * fy0 * fx1;
    a[2] = y1c * W_ + x0c;  w[2] = ly          * (1.0f - lx) * fy1 * fx0;
    a[3] = y1c * W_ + x1c;  w[3] = ly          * lx          * fy1 * fx1;
}

// ---------------- K2: fused deform conv (f16 MFMA) ----------------
__global__ __launch_bounds__(256, 4)
void deform_main(const _Float16* __restrict__ xt,
                 const _Float16* __restrict__ wof,
                 const float* __restrict__ b_off,
                 const _Float16* __restrict__ wdf,
                 const float* __restrict__ b_def,
                 float* __restrict__ out)
{
    __shared__ float off_lds[128 * 18];       // per-pixel offsets (this half-row)

    const int tid = threadIdx.x;
    const int lane = tid & 63;
    const int wv = tid >> 6;            // wave id: local px [wv*32, wv*32+32)
    const int lm = lane & 15;
    const int lq = lane >> 4;
    const int bid = blockIdx.x;                      // 2048
    const int uid = (bid & 7) * 256 + (bid >> 3);    // XCD band swizzle
    const int row = uid >> 1, half = uid & 1;
    const int b = row >> 8, y = row & 255;
    const int base = half * 128;                     // px window [base, base+128)
    const _Float16* __restrict__ xtb = xt + (size_t)b * HW_ * C_;

    // ================= phase 1: offsets via MFMA =================
    {
        floatx4 acc1[2][2];
#pragma unroll
        for (int pt = 0; pt < 2; ++pt)
#pragma unroll
            for (int nt = 0; nt < 2; ++nt) acc1[pt][nt] = (floatx4)0.0f;

#pragma unroll 1
        for (int tap = 0; tap < 9; ++tap) {
            const int dy = tap / 3 - 1, dx = tap % 3 - 1;
            const int ys = y + dy;
            if ((unsigned)ys < 256u) {
#pragma unroll
                for (int kc = 0; kc < 2; ++kc) {
                    half8 bfr[2];
#pragma unroll
                    for (int nt = 0; nt < 2; ++nt)
                        bfr[nt] = *(const half8*)(wof +
                            ((size_t)(((tap * 2 + kc) * 2 + nt) * 64 + lane)) * 8);
#pragma unroll
                    for (int pt = 0; pt < 2; ++pt) {
                        const int px_s = base + wv * 32 + pt * 16 + lm + dx;
                        const bool vld = (unsigned)px_s < 256u;
                        const int pxc = min(max(px_s, 0), 255);
                        uint4 t = *(const uint4*)(xtb +
                            ((size_t)ys * 256 + pxc) * 64 + kc * 32 + lq * 8);
                        if (!vld) { t.x = 0u; t.y = 0u; t.z = 0u; t.w = 0u; }
                        const half8 afr = __builtin_bit_cast(half8, t);
#pragma unroll
                        for (int nt = 0; nt < 2; ++nt)
                            acc1[pt][nt] = __builtin_amdgcn_mfma_f32_16x16x32_f16(
                                afr, bfr[nt], acc1[pt][nt], 0, 0, 0);
                    }
                }
            }
        }
#pragma unroll
        for (int nt = 0; nt < 2; ++nt) {
            const int j = nt * 16 + lm;
            if (j < 18) {
                const float bj = b_off[j];
#pragma unroll
                for (int pt = 0; pt < 2; ++pt) {
#pragma unroll
                    for (int r = 0; r < 4; ++r) {
                        const int lpx = wv * 32 + pt * 16 + lq * 4 + r;
                        off_lds[lpx * 18 + j] = acc1[pt][nt][r] + bj;
                    }
                }
            }
        }
    }
    __syncthreads();   // the ONLY barrier

    // ================= phase 2: per-thread f16 A-frag gather + MFMA =========
    floatx4 acc[2][4];
#pragma unroll
    for (int pt = 0; pt < 2; ++pt)
#pragma unroll
        for (int ot = 0; ot < 4; ++ot) acc[pt][ot] = (floatx4)0.0f;

#pragma unroll 1
    for (int tap = 0; tap < 9; ++tap) {
        const int ki = tap / 3, kj = tap % 3;
        int ca[2][4];
        h2 cw[2][4];
#pragma unroll
        for (int pt = 0; pt < 2; ++pt) {
            const int lpx = wv * 32 + pt * 16 + lm;
            const float ys = (float)(y + ki - 1) + off_lds[lpx * 18 + tap * 2];
            const float xs = (float)(base + lpx + kj - 1) + off_lds[lpx * 18 + tap * 2 + 1];
            float cwf[4];
            bilin_setup(ys, xs, ca[pt], cwf);
#pragma unroll
            for (int c = 0; c < 4; ++c) cw[pt][c] = (h2)((_Float16)cwf[c]);
        }

#pragma unroll
        for (int kc = 0; kc < 2; ++kc) {
            half8 bfr[4];
#pragma unroll
            for (int ot = 0; ot < 4; ++ot)
                bfr[ot] = *(const half8*)(wdf +
                    ((size_t)(((tap * 2 + kc) * 4 + ot) * 64 + lane)) * 8);

            const int sub = kc * 32 + lq * 8;
#pragma unroll
            for (int pt = 0; pt < 2; ++pt) {
                union Uc { uint4 u; h2 p[4]; } c0, c1, c2, c3;
                c0.u = *(const uint4*)(xtb + (size_t)ca[pt][0] * 64 + sub);
                c1.u = *(const uint4*)(xtb + (size_t)ca[pt][1] * 64 + sub);
                c2.u = *(const uint4*)(xtb + (size_t)ca[pt][2] * 64 + sub);
                c3.u = *(const uint4*)(xtb + (size_t)ca[pt][3] * 64 + sub);
                union Rr { h2 s[4]; half8 v; } r;
#pragma unroll
                for (int k = 0; k < 4; ++k)
                    r.s[k] = cw[pt][0] * c0.p[k] + cw[pt][1] * c1.p[k]
                           + cw[pt][2] * c2.p[k] + cw[pt][3] * c3.p[k];
#pragma unroll
                for (int ot = 0; ot < 4; ++ot)
                    acc[pt][ot] = __builtin_amdgcn_mfma_f32_16x16x32_f16(
                        r.v, bfr[ot], acc[pt][ot], 0, 0, 0);
            }
        }
    }

    // ================= epilogue: float4 stores =================
#pragma unroll
    for (int ot = 0; ot < 4; ++ot) {
        const int o = ot * 16 + lm;
        const float bd = b_def[o];
#pragma unroll
        for (int pt = 0; pt < 2; ++pt) {
            const int pxs = base + wv * 32 + pt * 16 + lq * 4;
            const floatx4 a = acc[pt][ot];
            float4 v = make_float4(a[0] + bd, a[1] + bd, a[2] + bd, a[3] + bd);
            *(float4*)&out[(((size_t)b * OUT_ + o) * H_ + y) * W_ + pxs] = v;
        }
    }
}

extern "C" void kernel_launch(void* const* d_in, const int* in_sizes, int n_in,
                              void* d_out, int out_size, void* d_ws, size_t ws_size,
                              hipStream_t stream)
{
    const float* x     = (const float*)d_in[0];
    const float* w_off = (const float*)d_in[1];
    const float* b_off = (const float*)d_in[2];
    const float* w_def = (const float*)d_in[3];
    const float* b_def = (const float*)d_in[4];
    float* out = (float*)d_out;

    _Float16* xt  = (_Float16*)d_ws;
    _Float16* wof = (_Float16*)((char*)d_ws + WOFF_OFF);
    _Float16* wdf = (_Float16*)((char*)d_ws + WDEF_OFF);

    transpose_x<<<dim3(B_ * H_ * 4), dim3(256), 0, stream>>>(
        x, xt, w_off, w_def, wof, wdf);
    deform_main<<<dim3(B_ * H_ * 2), dim3(256), 0, stream>>>(
        xt, wof, b_off, wdf, b_def, out);
}